// Round 12
// baseline (842.674 us; speedup 1.0000x reference)
//
#include <hip/hip_runtime.h>

typedef unsigned short u16;
typedef unsigned int u32;

#define BATCH 4
#define CDIM 384
#define IMG 128
#define HW 16384
#define QKVC 1152
#define NHEADS 8
#define CHD 48
#define DD2 96
#define KFIN 768

typedef __attribute__((ext_vector_type(8))) short bf16x8;
typedef __attribute__((ext_vector_type(4))) float f32x4;

// ---------- bf16 helpers (manual RNE) ----------
__device__ __forceinline__ u16 f2bf(float f){
  union { float f; u32 u; } v; v.f = f;
  u32 u = v.u;
  u32 r = (u + 0x7fffu + ((u >> 16) & 1u)) >> 16;
  return (u16)r;
}
__device__ __forceinline__ float bf2f(u16 h){
  union { u32 u; float f; } v; v.u = ((u32)h) << 16;
  return v.f;
}

// ---------- workspace layout (bytes) ----------
#define OFF_QKVX  ((size_t)0)                         // u16 [4][1152][16384]; v-slot (rows 768..1151) = Vt0
#define OFF_QKVM  ((size_t)150994944)                 // u16 [4][1152][16384]; v-slot = T parity-1 scratch, then Vt1
#define OFF_T     ((size_t)301989888)                 // u16 [1152][16384] = T parity-0
#define OFF_SSQ   ((size_t)339738624)                 // f32 [2][4][1152] (only ch<768 written/read)
#define OFF_S     ((size_t)339775488)                 // f32 [2][4][8][48][96]
#define OFF_ATTN  ((size_t)340955136)                 // f32 [2][4][8][48][96]
#define OFF_AFINB ((size_t)342134784)                 // bf16 [4][384][768]
#define OFF_W2    ((size_t)344494080)                 // f32 [384][768]
#define OFF_B2    ((size_t)345673728)                 // f32 [384]
#define OFF_WB    ((size_t)345675264)                 // bf16 [1152][384]

// ---------- global_load_lds helper (16B per lane, dest = base + lane*16) ----------
typedef __attribute__((address_space(1))) const u32 gas_u32;
typedef __attribute__((address_space(3))) u32 las_u32;
__device__ __forceinline__ void gl_lds16(const u16* g, u16* l){
  __builtin_amdgcn_global_load_lds((gas_u32*)g, (las_u32*)l, 16, 0, 0);
}

// ---------- T ping-pong row addressing ----------
// parity 0: contiguous T0 region. parity 1: qkvm v-row slots of b'=0..2 (dead until k_tail's vt).
__device__ __forceinline__ u16* t_row(u16* T0, u16* qkvm, int par, int ch){
  if (par == 0) return T0 + (size_t)ch * HW;
  int bq = ch / 384;
  int rr = ch - bq * 384;
  return qkvm + ((size_t)bq * QKVC + 2 * CDIM + rr) * HW;
}

// ---------- depthwise row loader (18-wide halo row, vectorized) ----------
__device__ __forceinline__ void loadrow(const u16* __restrict__ src, int r, int cg, float* o){
  if ((unsigned)r >= IMG){
    #pragma unroll
    for (int i = 0; i < 18; i++) o[i] = 0.f;
    return;
  }
  const u16* p = src + (size_t)r * IMG + cg * 16;
  uint4 v0 = *(const uint4*)p;
  uint4 v1 = *(const uint4*)(p + 8);
  u32 ww[8] = {v0.x, v0.y, v0.z, v0.w, v1.x, v1.y, v1.z, v1.w};
  #pragma unroll
  for (int i = 0; i < 8; i++){
    union { u32 u; float f; } lo, hi;
    lo.u = ww[i] << 16;
    hi.u = ww[i] & 0xffff0000u;
    o[1 + 2 * i] = lo.f;
    o[2 + 2 * i] = hi.f;
  }
  o[0]  = (cg > 0) ? bf2f(p[-1]) : 0.f;
  o[17] = (cg < 7) ? bf2f(p[16]) : 0.f;
}

// ---------- K_stage: fat pipelined dispatch.
// roles: [logits(t-7) | pw(t-1) | dw(t-2) | cvt(t) | w2(t=0 only, 1728 blocks)]
__global__ void __launch_bounds__(256) k_stage(
    int t, int nlog, int npw, int ndw, int ncvt,
    const u16* __restrict__ Wb, u16* __restrict__ Bt,
    u16* __restrict__ T0, u16* __restrict__ qkvx, u16* __restrict__ qkvm,
    const float* __restrict__ x, const float* __restrict__ msg,
    const float* __restrict__ dww, float* __restrict__ ssq,
    float* __restrict__ S,
    const float* __restrict__ proj, const float* __restrict__ lin,
    const float* __restrict__ linb, const float* __restrict__ qkvw,
    float* __restrict__ W2, float* __restrict__ b2, u16* __restrict__ Wbw){
  __shared__ __align__(16) u16 smem[16384];   // 32 KB, aliased per role
  int bid = blockIdx.x;
  int tid = threadIdx.x;

  if (bid < nlog){
    // ======== role LOGITS: batch b = t-7, 256 blocks, LCHUNK 512, 2x-unrolled ========
    int b = t - 7;
    int nc = bid & 31;
    int h = bid >> 5;
    int w = tid >> 6, lane = tid & 63;
    int wy = w >> 1, wx = w & 1;
    int lm = lane & 15, quad = lane >> 4;

    const u16* ap[3]; const u16* bp[3];
    #pragma unroll
    for (int i = 0; i < 3; i++){
      int g = wy * 48 + i * 16 + lm;
      int c = (g < 48) ? g : g - 48;
      ap[i] = ((g < 48) ? qkvx : qkvm) + ((size_t)b * QKVC + h * CHD + c) * HW;
      int d = wx * 48 + i * 16 + lm;
      int cc = (d < 48) ? d : d - 48;
      bp[i] = ((d < 48) ? qkvx : qkvm) + ((size_t)b * QKVC + CDIM + h * CHD + cc) * HW;
    }
    f32x4 acc[3][3];
    #pragma unroll
    for (int i = 0; i < 3; i++)
      #pragma unroll
      for (int j = 0; j < 3; j++) acc[i][j] = (f32x4){0.f,0.f,0.f,0.f};

    int nbeg = nc * 512 + quad * 8;
    int nend = nc * 512 + 512;
    for (int n = nbeg; n < nend; n += 64){
      bf16x8 af0[3], bf0[3], af1[3], bf1[3];
      #pragma unroll
      for (int i = 0; i < 3; i++){
        af0[i] = *(const bf16x8*)(ap[i] + n);
        af1[i] = *(const bf16x8*)(ap[i] + n + 32);
      }
      #pragma unroll
      for (int j = 0; j < 3; j++){
        bf0[j] = *(const bf16x8*)(bp[j] + n);
        bf1[j] = *(const bf16x8*)(bp[j] + n + 32);
      }
      #pragma unroll
      for (int i = 0; i < 3; i++)
        #pragma unroll
        for (int j = 0; j < 3; j++)
          acc[i][j] = __builtin_amdgcn_mfma_f32_16x16x32_bf16(af0[i], bf0[j], acc[i][j], 0, 0, 0);
      #pragma unroll
      for (int i = 0; i < 3; i++)
        #pragma unroll
        for (int j = 0; j < 3; j++)
          acc[i][j] = __builtin_amdgcn_mfma_f32_16x16x32_bf16(af1[i], bf1[j], acc[i][j], 0, 0, 0);
    }
    #pragma unroll
    for (int i = 0; i < 3; i++){
      #pragma unroll
      for (int r = 0; r < 4; r++){
        int g = wy * 48 + i * 16 + quad * 4 + r;
        int iq = (g >= 48) ? 1 : 0;
        int c = iq ? g - 48 : g;
        float* Sp = S + (((size_t)(iq * BATCH + b) * NHEADS + h) * CHD + c) * DD2;
        #pragma unroll
        for (int j = 0; j < 3; j++)
          atomicAdd(&Sp[wx * 48 + j * 16 + lm], acc[i][j][r]);
      }
    }

  } else if (bid < nlog + npw){
    // ======== role PW: T[par] = Wb @ Bt[z]^T,  z = t-1 ========
    int pb = bid - nlog;
    int z = t - 1, par = z & 1;
    const u16* B = Bt + (size_t)z * HW * CDIM;
    u16* As = smem;            // [2][4096] u16
    u16* Bs = smem + 8192;
    int swz = (pb & 7) * 144 + (pb >> 3);   // bijective XCD swizzle (1152 % 8 == 0)
    int bx = swz % 9, by = swz / 9;
    int m0 = bx * 128, n0 = by * 128;
    int w = tid >> 6, lane = tid & 63;
    int wy = w >> 1, wx = w & 1;
    int lm = lane & 15, q = lane >> 4;

    int srow = w * 16 + (lane >> 2);
    int scol = (lane & 3) * 8;
    const u16* ga = Wb + (size_t)(m0 + srow) * CDIM + scol;
    const u16* gb = B + (size_t)(n0 + srow) * CDIM + scol;
    u16* la = As + srow * 32 + scol;
    u16* lb = Bs + srow * 32 + scol;

    f32x4 acc[4][4];
    #pragma unroll
    for (int i = 0; i < 4; i++)
      #pragma unroll
      for (int j = 0; j < 4; j++) acc[i][j] = (f32x4){0.f,0.f,0.f,0.f};

#define PW_STAGE(buf, k0) do{ \
      gl_lds16(ga + (k0),             la + (buf) * 4096); \
      gl_lds16(ga + 64*CDIM + (k0),   la + (buf) * 4096 + 2048); \
      gl_lds16(gb + (k0),             lb + (buf) * 4096); \
      gl_lds16(gb + 64*CDIM + (k0),   lb + (buf) * 4096 + 2048); \
    }while(0)

    PW_STAGE(0, 0);
    __syncthreads();
    int cur = 0;
    for (int kt = 0; kt < 12; kt++){
      if (kt < 11) PW_STAGE(cur ^ 1, (kt + 1) * 32);
      bf16x8 af[4], bfr[4];
      #pragma unroll
      for (int i = 0; i < 4; i++)
        af[i] = *(const bf16x8*)&As[cur * 4096 + (wy * 64 + i * 16 + lm) * 32 + q * 8];
      #pragma unroll
      for (int j = 0; j < 4; j++)
        bfr[j] = *(const bf16x8*)&Bs[cur * 4096 + (wx * 64 + j * 16 + lm) * 32 + q * 8];
      #pragma unroll
      for (int i = 0; i < 4; i++)
        #pragma unroll
        for (int j = 0; j < 4; j++)
          acc[i][j] = __builtin_amdgcn_mfma_f32_16x16x32_bf16(af[i], bfr[j], acc[i][j], 0, 0, 0);
      __syncthreads();
      cur ^= 1;
    }
#undef PW_STAGE
    #pragma unroll
    for (int i = 0; i < 4; i++){
      #pragma unroll
      for (int r = 0; r < 4; r++){
        int row = m0 + wy * 64 + i * 16 + q * 4 + r;
        u16* cp = t_row(T0, qkvm, par, row) + n0 + wx * 64 + lm;
        #pragma unroll
        for (int j = 0; j < 4; j++)
          cp[j * 16] = f2bf(acc[i][j][r]);
      }
    }

  } else if (bid < nlog + npw + ndw){
    // ======== role DW: depthwise 3x3 on T[z&1], z = t-2 ========
    int ch = bid - nlog - npw;
    int z = t - 2, par = z & 1;
    const u16* src = t_row(T0, qkvm, par, ch);
    u16* dst;
    if (ch < 2 * CDIM){
      u16* qd = ((z >> 2) ? qkvm : qkvx) + (size_t)(z & 3) * QKVC * HW;
      dst = qd + (size_t)ch * HW;
    } else {
      dst = Bt + (size_t)z * HW * CDIM + (size_t)(ch - 2 * CDIM) * HW;
    }
    float w[9];
    #pragma unroll
    for (int t9 = 0; t9 < 9; t9++) w[t9] = dww[ch * 9 + t9];
    int rg = tid >> 3, cg = tid & 7;
    int r0 = rg * 4;
    float ra[18], rb[18], rc[18];
    loadrow(src, r0 - 1, cg, ra);
    loadrow(src, r0,     cg, rb);
    float ss = 0.f;
    #pragma unroll
    for (int rr = 0; rr < 4; rr++){
      int r = r0 + rr;
      loadrow(src, r + 1, cg, rc);
      u32 pk[8];
      #pragma unroll
      for (int xx = 0; xx < 16; xx++){
        float a2 = w[0] * ra[xx];
        a2 = fmaf(w[1], ra[xx + 1], a2);
        a2 = fmaf(w[2], ra[xx + 2], a2);
        a2 = fmaf(w[3], rb[xx],     a2);
        a2 = fmaf(w[4], rb[xx + 1], a2);
        a2 = fmaf(w[5], rb[xx + 2], a2);
        a2 = fmaf(w[6], rc[xx],     a2);
        a2 = fmaf(w[7], rc[xx + 1], a2);
        a2 = fmaf(w[8], rc[xx + 2], a2);
        ss = fmaf(a2, a2, ss);
        u16 hv = f2bf(a2);
        if (xx & 1) pk[xx >> 1] |= (u32)hv << 16;
        else        pk[xx >> 1]  = (u32)hv;
      }
      *(uint4*)(dst + (size_t)r * IMG + cg * 16)     = *(uint4*)&pk[0];
      *(uint4*)(dst + (size_t)r * IMG + cg * 16 + 8) = *(uint4*)&pk[4];
      #pragma unroll
      for (int ii = 0; ii < 18; ii++){ ra[ii] = rb[ii]; rb[ii] = rc[ii]; }
    }
    if (ch < 2 * CDIM){
      float* red = (float*)smem;
      red[tid] = ss;
      __syncthreads();
      for (int s = 128; s > 0; s >>= 1){
        if (tid < s) red[tid] += red[tid + s];
        __syncthreads();
      }
      if (tid == 0) ssq[(size_t)z * QKVC + ch] = red[0];
    }

  } else if (bid < nlog + npw + ndw + ncvt){
    // ======== role CVT: fp32 [c][n] -> bf16 [n][c] into Bt[z], z = t ========
    int cb = bid - nlog - npw - ndw;   // 0..767
    int z = t;
    const float* src = (z < 4 ? x : msg) + (size_t)(z & 3) * CDIM * HW;
    u16* dstz = Bt + (size_t)z * HW * CDIM;
    int n0 = (cb & 127) * 128;
    int c0 = (cb >> 7) * 64;
    u16 (*tile)[130] = (u16(*)[130])smem;   // 64 x 130 u16
    #pragma unroll
    for (int i = 0; i < 8; i++){
      int c = (tid >> 5) + i * 8;
      int nq = tid & 31;
      float4 v = *(const float4*)(src + (size_t)(c0 + c) * HW + n0 + nq * 4);
      u32 p0 = (u32)f2bf(v.x) | ((u32)f2bf(v.y) << 16);
      u32 p1 = (u32)f2bf(v.z) | ((u32)f2bf(v.w) << 16);
      *(u32*)&tile[c][nq * 4]     = p0;
      *(u32*)&tile[c][nq * 4 + 2] = p1;
    }
    __syncthreads();
    #pragma unroll
    for (int u = 0; u < 2; u++){
      int idx = tid + u * 256;            // 0..511
      int n = idx >> 2, j = idx & 3;
      u32 pk[8];
      #pragma unroll
      for (int p = 0; p < 8; p++)
        pk[p] = (u32)tile[j * 16 + 2 * p][n] | ((u32)tile[j * 16 + 2 * p + 1][n] << 16);
      u16* dp = dstz + (size_t)(n0 + n) * CDIM + c0 + j * 16;
      *(uint4*)dp       = *(uint4*)&pk[0];
      *(uint4*)(dp + 8) = *(uint4*)&pk[4];
    }

  } else {
    // ======== role W2 (t=0 only, 1728 blocks -> 442368 threads): ========
    // W2 = proj @ lin (294912); b2 = proj @ lin_b (384); Wb = bf16(qkv_w) (442368)
    int idx = (bid - nlog - npw - ndw - ncvt) * 256 + tid;
    if (idx < CDIM * KFIN){
      int o = idx / KFIN, d = idx % KFIN;
      float acc = 0.f;
      for (int c = 0; c < CDIM; c++)
        acc = fmaf(proj[o * CDIM + c], lin[c * KFIN + d], acc);
      W2[idx] = acc;
    }
    if (idx < CDIM){
      float acc = 0.f;
      for (int c = 0; c < CDIM; c++)
        acc = fmaf(proj[idx * CDIM + c], linb[c], acc);
      b2[idx] = acc;
    }
    if (idx < QKVC * CDIM) Wbw[idx] = f2bf(qkvw[idx]);
  }
}

// ---------- K_tail: fused [logits b=3 (256 blocks, LCHUNK 512, 4x-unrolled) | v-transpose (8192 blocks)] ----------
__global__ void __launch_bounds__(256) k_tail(u16* __restrict__ qkvx,
                                              u16* __restrict__ qkvm,
                                              float* __restrict__ S,
                                              const u16* __restrict__ Bt){
  __shared__ u16 tile[48][136];
  int bid = blockIdx.x;
  int tid = threadIdx.x;

  if (bid < 256){
    // ---- logits batch 3: S += q . k over 512-n chunk; 4x unrolled, order preserved ----
    int b = 3;
    int nc = bid & 31;
    int h = bid >> 5;
    int w = tid >> 6, lane = tid & 63;
    int wy = w >> 1, wx = w & 1;
    int lm = lane & 15, quad = lane >> 4;

    const u16* ap[3]; const u16* bp[3];
    #pragma unroll
    for (int i = 0; i < 3; i++){
      int g = wy * 48 + i * 16 + lm;
      int c = (g < 48) ? g : g - 48;
      ap[i] = ((g < 48) ? qkvx : qkvm) + ((size_t)b * QKVC + h * CHD + c) * HW;
      int d = wx * 48 + i * 16 + lm;
      int cc = (d < 48) ? d : d - 48;
      bp[i] = ((d < 48) ? qkvx : qkvm) + ((size_t)b * QKVC + CDIM + h * CHD + cc) * HW;
    }
    f32x4 acc[3][3];
    #pragma unroll
    for (int i = 0; i < 3; i++)
      #pragma unroll
      for (int j = 0; j < 3; j++) acc[i][j] = (f32x4){0.f,0.f,0.f,0.f};

    int nbeg = nc * 512 + quad * 8;
    int nend = nc * 512 + 512;
    for (int n = nbeg; n < nend; n += 128){
      bf16x8 af[4][3], bfr[4][3];
      #pragma unroll
      for (int u = 0; u < 4; u++){
        #pragma unroll
        for (int i = 0; i < 3; i++){
          af[u][i]  = *(const bf16x8*)(ap[i] + n + u * 32);
          bfr[u][i] = *(const bf16x8*)(bp[i] + n + u * 32);
        }
      }
      #pragma unroll
      for (int u = 0; u < 4; u++)
        #pragma unroll
        for (int i = 0; i < 3; i++)
          #pragma unroll
          for (int j = 0; j < 3; j++)
            acc[i][j] = __builtin_amdgcn_mfma_f32_16x16x32_bf16(af[u][i], bfr[u][j], acc[i][j], 0, 0, 0);
    }
    #pragma unroll
    for (int i = 0; i < 3; i++){
      #pragma unroll
      for (int r = 0; r < 4; r++){
        int g = wy * 48 + i * 16 + quad * 4 + r;
        int iq = (g >= 48) ? 1 : 0;
        int c = iq ? g - 48 : g;
        float* Sp = S + (((size_t)(iq * BATCH + b) * NHEADS + h) * CHD + c) * DD2;
        #pragma unroll
        for (int j = 0; j < 3; j++)
          atomicAdd(&Sp[wx * 48 + j * 16 + lm], acc[i][j][r]);
      }
    }
  } else {
    // ---- vt: v [c][n] (in Bt[z]) -> Vt[n][d] into qkvx/qkvm v-slots (low-conflict mapping) ----
    int v = bid - 256;
    int nb = v & 127;
    int h = (v >> 7) & 7;
    int z = v >> 10;
    int inp = z >> 2, b = z & 3;
    const u16* vcn = Bt + (size_t)z * HW * CDIM;
    int n0 = nb * 128;
    u16* vt = (h < 4 ? qkvx : qkvm) + ((size_t)b * QKVC + 2 * CDIM) * HW;  // [16384][384]
    int dbase = (h & 3) * 96 + inp * 48;
    #pragma unroll
    for (int j = 0; j < 3; j++){
      int i = tid + j * 256;            // uint4 index < 768
      int row = i >> 4, c8 = i & 15;
      uint4 vv = *(const uint4*)(vcn + (size_t)(h * 48 + row) * HW + n0 + c8 * 8);
      *(uint4*)&tile[row][c8 * 8] = vv;
    }
    __syncthreads();
    int n = tid >> 1, half = tid & 1;
    u16* dstp = vt + (size_t)(n0 + n) * CDIM + dbase + half * 24;
    #pragma unroll
    for (int u = 0; u < 3; u++){
      u32 pk[4];
      #pragma unroll
      for (int p = 0; p < 4; p++){
        int c = half * 24 + u * 8 + p * 2;
        pk[p] = (u32)tile[c][n] | ((u32)tile[c + 1][n] << 16);
      }
      *(uint4*)(dstp + u * 8) = *(uint4*)pk;
    }
  }
}

// ---------- K4a: scale by norms+temperature, softmax over d ----------
__global__ void __launch_bounds__(128) k_softmax(const float* __restrict__ S,
                                                 const float* __restrict__ ssq,
                                                 const float* __restrict__ temp,
                                                 float* __restrict__ attn){
  int row = blockIdx.x;
  int c = row % CHD;
  int h = (row / CHD) % NHEADS;
  int b = (row / (CHD * NHEADS)) % BATCH;
  int iq = row / (CHD * NHEADS * BATCH);
  int tid = threadIdx.x;
  __shared__ float sh[128];
  const float* Sp = S + (size_t)row * DD2;
  float ssq_q = ssq[(iq * BATCH + b) * QKVC + h * CHD + c];
  float nq = fmaxf(sqrtf(ssq_q), 1e-12f);
  float tmp = temp[h];
  float logit = -1e30f;
  int d = tid;
  if (d < DD2){
    float ssq_k = ssq[((d < CHD ? 0 : 1) * BATCH + b) * QKVC + CDIM + h * CHD + (d % CHD)];
    float nk = fmaxf(sqrtf(ssq_k), 1e-12f);
    logit = Sp[d] * tmp / (nq * nk);
  }
  sh[tid] = logit; __syncthreads();
  for (int s = 64; s > 0; s >>= 1){
    if (tid < s) sh[tid] = fmaxf(sh[tid], sh[tid + s]);
    __syncthreads();
  }
  float mx = sh[0]; __syncthreads();
  float e = (d < DD2) ? expf(logit - mx) : 0.f;
  sh[tid] = e; __syncthreads();
  for (int s = 64; s > 0; s >>= 1){
    if (tid < s) sh[tid] += sh[tid + s];
    __syncthreads();
  }
  float sum = sh[0];
  if (d < DD2) attn[(size_t)row * DD2 + d] = e / sum;
}

// ---------- K4b: AfinB (bf16) = W2-folded attention ----------
__global__ void __launch_bounds__(128) k_mmat(const float* __restrict__ attn,
                                              const float* __restrict__ W2,
                                              u16* __restrict__ AfinB){
  int oz = blockIdx.x;
  int h = blockIdx.y;
  int b = blockIdx.z;
  __shared__ float a1[CHD * DD2];
  __shared__ float a2[CHD * DD2];
  int tid = threadIdx.x;
  const float* A1 = attn + ((size_t)(0 * BATCH + b) * NHEADS + h) * CHD * DD2;
  const float* A2 = attn + ((size_t)(1 * BATCH + b) * NHEADS + h) * CHD * DD2;
  for (int i = tid; i < CHD * DD2; i += 128){ a1[i] = A1[i]; a2[i] = A2[i]; }
  __syncthreads();
  int e = tid;
  if (e < DD2){
    for (int oo = 0; oo < 8; oo++){
      int o = oz * 8 + oo;
      float acc = 0.f;
      #pragma unroll 4
      for (int cc = 0; cc < CHD; cc++){
        acc = fmaf(W2[o * KFIN + h * CHD + cc],        a1[cc * DD2 + e], acc);
        acc = fmaf(W2[o * KFIN + CDIM + h * CHD + cc], a2[cc * DD2 + e], acc);
      }
      AfinB[((size_t)b * CDIM + o) * KFIN + h * DD2 + e] = f2bf(acc);
    }
  }
}

// ---------- K_fin: out[b][384][16384] = AfinB[b] @ Vt[b]^T + b2 ----------
__global__ void __launch_bounds__(256) k_fin(const u16* __restrict__ AfB,
                                             const u16* __restrict__ qkvx,
                                             const u16* __restrict__ qkvm,
                                             const float* __restrict__ b2,
                                             float* __restrict__ out){
  __shared__ __align__(16) u16 As[2 * 4096];
  __shared__ __align__(16) u16 Bs[2 * 4096];
  int orig = blockIdx.x;
  int swz = (orig & 7) * 192 + (orig >> 3);   // bijective: 1536 % 8 == 0
  int m = swz % 3;
  int rest = swz / 3;
  int n0 = (rest & 127) * 128;
  int bz = rest >> 7;
  int m0 = m * 128;
  int tid = threadIdx.x;
  int w = tid >> 6, lane = tid & 63;
  int wy = w >> 1, wx = w & 1;
  int lm = lane & 15, q = lane >> 4;

  int srow = w * 16 + (lane >> 2);
  int scol = (lane & 3) * 8;
  const u16* A = AfB + (size_t)bz * CDIM * KFIN;
  const u16* ga  = A + (size_t)(m0 + srow) * KFIN + scol;
  const u16* gb0 = qkvx + ((size_t)bz * QKVC + 2 * CDIM) * HW + (size_t)(n0 + srow) * CDIM + scol;
  const u16* gb1 = qkvm + ((size_t)bz * QKVC + 2 * CDIM) * HW + (size_t)(n0 + srow) * CDIM + scol;
  u16* la = As + srow * 32 + scol;
  u16* lb = Bs + srow * 32 + scol;

  f32x4 acc[4][4];
  #pragma unroll
  for (int i = 0; i < 4; i++)
    #pragma unroll
    for (int j = 0; j < 4; j++) acc[i][j] = (f32x4){0.f,0.f,0.f,0.f};

#define FIN_STAGE(buf, t) do{ \
    int hp_ = (t) >= 12; \
    int k0_ = ((t) - hp_ * 12) * 32; \
    const u16* gb_ = hp_ ? gb1 : gb0; \
    gl_lds16(ga + hp_ * CDIM + k0_,            la + (buf) * 4096); \
    gl_lds16(ga + hp_ * CDIM + k0_ + 64*KFIN,  la + (buf) * 4096 + 2048); \
    gl_lds16(gb_ + k0_,                        lb + (buf) * 4096); \
    gl_lds16(gb_ + k0_ + 64*CDIM,              lb + (buf) * 4096 + 2048); \
  }while(0)

  FIN_STAGE(0, 0);
  __syncthreads();
  int cur = 0;
  for (int t = 0; t < 24; t++){
    if (t < 23) FIN_STAGE(cur ^ 1, t + 1);
    bf16x8 af[4], bfr[4];
    #pragma unroll
    for (int i = 0; i < 4; i++)
      af[i] = *(const bf16x8*)&As[cur * 4096 + (wy * 64 + i * 16 + lm) * 32 + q * 8];
    #pragma unroll
    for (int j = 0; j < 4; j++)
      bfr[j] = *(const bf16x8*)&Bs[cur * 4096 + (wx * 64 + j * 16 + lm) * 32 + q * 8];
    #pragma unroll
    for (int i = 0; i < 4; i++)
      #pragma unroll
      for (int j = 0; j < 4; j++)
        acc[i][j] = __builtin_amdgcn_mfma_f32_16x16x32_bf16(af[i], bfr[j], acc[i][j], 0, 0, 0);
    __syncthreads();
    cur ^= 1;
  }
#undef FIN_STAGE
  #pragma unroll
  for (int i = 0; i < 4; i++){
    #pragma unroll
    for (int r = 0; r < 4; r++){
      int row = m0 + wy * 64 + i * 16 + q * 4 + r;
      float bv = b2[row];
      float* cp = out + (size_t)bz * CDIM * HW + (size_t)row * HW + n0 + wx * 64 + lm;
      #pragma unroll
      for (int j = 0; j < 4; j++)
        cp[j * 16] = acc[i][j][r] + bv;
    }
  }
}

extern "C" void kernel_launch(void* const* d_in, const int* in_sizes, int n_in,
                              void* d_out, int out_size, void* d_ws, size_t ws_size,
                              hipStream_t stream){
  const float* x      = (const float*)d_in[0];
  const float* msg    = (const float*)d_in[1];
  const float* temp   = (const float*)d_in[2];
  const float* qkv_w  = (const float*)d_in[3];
  const float* dw_w   = (const float*)d_in[4];
  const float* proj_w = (const float*)d_in[5];
  const float* lin_w  = (const float*)d_in[6];
  const float* lin_b  = (const float*)d_in[7];
  float* out = (float*)d_out;

  char* ws = (char*)d_ws;
  u16*   qkvx  = (u16*)(ws + OFF_QKVX);
  u16*   qkvm  = (u16*)(ws + OFF_QKVM);
  u16*   T0    = (u16*)(ws + OFF_T);
  float* ssq   = (float*)(ws + OFF_SSQ);
  float* S     = (float*)(ws + OFF_S);
  float* attn  = (float*)(ws + OFF_ATTN);
  u16*   AfinB = (u16*)(ws + OFF_AFINB);
  float* W2    = (float*)(ws + OFF_W2);
  float* b2    = (float*)(ws + OFF_B2);
  u16*   Wb    = (u16*)(ws + OFF_WB);

  // Bt scratch lives in d_out (exactly out_size). Timeline per z (pipelined across dispatches):
  //   cvt(z)@t=z writes Bt[z] -> pw(z)@t=z+1 reads it -> dw(z)@t=z+2 overwrites it with v [c][n]
  //   -> k_tail's vt reads it -> k_fin finally overwrites d_out with the real output.
  //   w2 role runs inside t=0 (1728 blocks; Wb = 442368 elements; Wb first consumed by pw(0)@t=1).
  //   logits(b)@t=b+7 for b=0..2 (qkvm half of batch b written by dw(b+4)@t=b+6; within-dispatch
  //   writes are disjoint from logits reads). logits b=3 stays in k_tail.
  u16* Bt = (u16*)d_out;

  hipMemsetAsync(ws + OFF_S, 0, (OFF_ATTN - OFF_S), stream);

  // 3-deep software pipeline: dispatch t runs logits(t-7) | pw(t-1) | dw(t-2) | cvt(t) | w2(t=0).
  for (int t = 0; t < 10; t++){
    int nlog = (t >= 7) ? 256 : 0;
    int npw  = (t >= 1 && t <= 8) ? 1152 : 0;
    int ndw  = (t >= 2) ? 1152 : 0;
    int ncvt = (t < 8) ? 768 : 0;
    int nw2  = (t == 0) ? 1728 : 0;
    k_stage<<<dim3(nlog + npw + ndw + ncvt + nw2), dim3(256), 0, stream>>>(
        t, nlog, npw, ndw, ncvt, Wb, Bt, T0, qkvx, qkvm, x, msg, dw_w, ssq, S,
        proj_w, lin_w, lin_b, qkv_w, W2, b2, Wb);
  }

  k_tail<<<dim3(256 + 8192), dim3(256), 0, stream>>>(qkvx, qkvm, S, Bt);
  k_softmax<<<dim3(2 * BATCH * NHEADS * CHD), dim3(128), 0, stream>>>(S, ssq, temp, attn);
  k_mmat<<<dim3(CDIM / 8, NHEADS, BATCH), dim3(128), 0, stream>>>(attn, W2, AfinB);
  k_fin<<<dim3(3 * (HW / 128) * BATCH), dim3(256), 0, stream>>>(
      AfinB, qkvx, qkvm, b2, out);
}

// Round 13
// 811.941 us; speedup vs baseline: 1.0379x; 1.0379x over previous
//
#include <hip/hip_runtime.h>

typedef unsigned short u16;
typedef unsigned int u32;

#define BATCH 4
#define CDIM 384
#define IMG 128
#define HW 16384
#define QKVC 1152
#define NHEADS 8
#define CHD 48
#define DD2 96
#define KFIN 768

typedef __attribute__((ext_vector_type(8))) short bf16x8;
typedef __attribute__((ext_vector_type(4))) float f32x4;

// ---------- bf16 helpers (manual RNE) ----------
__device__ __forceinline__ u16 f2bf(float f){
  union { float f; u32 u; } v; v.f = f;
  u32 u = v.u;
  u32 r = (u + 0x7fffu + ((u >> 16) & 1u)) >> 16;
  return (u16)r;
}
__device__ __forceinline__ float bf2f(u16 h){
  union { u32 u; float f; } v; v.u = ((u32)h) << 16;
  return v.f;
}

// ---------- workspace layout (bytes) ----------
#define OFF_QKVX  ((size_t)0)                         // u16 [4][1152][16384]; v-slot (rows 768..1151) = Vt0
#define OFF_QKVM  ((size_t)150994944)                 // u16 [4][1152][16384]; v-slot = T parity-1 scratch, then Vt1
#define OFF_T     ((size_t)301989888)                 // u16 [1152][16384] = T parity-0
#define OFF_SSQ   ((size_t)339738624)                 // f32 [2][4][1152] (only ch<768 written/read)
#define OFF_S     ((size_t)339775488)                 // f32 [2][4][8][48][96]
#define OFF_ATTN  ((size_t)340955136)                 // f32 [2][4][8][48][96]
#define OFF_AFINB ((size_t)342134784)                 // bf16 [4][384][768]
#define OFF_W2    ((size_t)344494080)                 // f32 [384][768]
#define OFF_B2    ((size_t)345673728)                 // f32 [384]
#define OFF_WB    ((size_t)345675264)                 // bf16 [1152][384]

// ---------- global_load_lds helper (16B per lane, dest = base + lane*16) ----------
typedef __attribute__((address_space(1))) const u32 gas_u32;
typedef __attribute__((address_space(3))) u32 las_u32;
__device__ __forceinline__ void gl_lds16(const u16* g, u16* l){
  __builtin_amdgcn_global_load_lds((gas_u32*)g, (las_u32*)l, 16, 0, 0);
}

// ---------- T ping-pong row addressing ----------
// parity 0: contiguous T0 region. parity 1: qkvm v-row slots of b'=0..2 (dead until k_tail's vt).
__device__ __forceinline__ u16* t_row(u16* T0, u16* qkvm, int par, int ch){
  if (par == 0) return T0 + (size_t)ch * HW;
  int bq = ch / 384;
  int rr = ch - bq * 384;
  return qkvm + ((size_t)bq * QKVC + 2 * CDIM + rr) * HW;
}

// ---------- K0: W2 = proj_w @ lin_w ; b2 = proj_w @ lin_b ; Wb = bf16(qkv_w) ----------
__global__ void __launch_bounds__(256) k_w2(const float* __restrict__ proj,
                                            const float* __restrict__ lin,
                                            const float* __restrict__ linb,
                                            const float* __restrict__ qkvw,
                                            float* __restrict__ W2,
                                            float* __restrict__ b2,
                                            u16* __restrict__ Wb){
  int idx = blockIdx.x * 256 + threadIdx.x;
  if (idx < CDIM * KFIN){
    int o = idx / KFIN, d = idx % KFIN;
    float acc = 0.f;
    for (int c = 0; c < CDIM; c++)
      acc = fmaf(proj[o * CDIM + c], lin[c * KFIN + d], acc);
    W2[idx] = acc;
  }
  if (idx < CDIM){
    float acc = 0.f;
    for (int c = 0; c < CDIM; c++)
      acc = fmaf(proj[idx * CDIM + c], linb[c], acc);
    b2[idx] = acc;
  }
  if (idx < QKVC * CDIM) Wb[idx] = f2bf(qkvw[idx]);
}

// ---------- depthwise row loader (18-wide halo row, vectorized) ----------
__device__ __forceinline__ void loadrow(const u16* __restrict__ src, int r, int cg, float* o){
  if ((unsigned)r >= IMG){
    #pragma unroll
    for (int i = 0; i < 18; i++) o[i] = 0.f;
    return;
  }
  const u16* p = src + (size_t)r * IMG + cg * 16;
  uint4 v0 = *(const uint4*)p;
  uint4 v1 = *(const uint4*)(p + 8);
  u32 ww[8] = {v0.x, v0.y, v0.z, v0.w, v1.x, v1.y, v1.z, v1.w};
  #pragma unroll
  for (int i = 0; i < 8; i++){
    union { u32 u; float f; } lo, hi;
    lo.u = ww[i] << 16;
    hi.u = ww[i] & 0xffff0000u;
    o[1 + 2 * i] = lo.f;
    o[2 + 2 * i] = hi.f;
  }
  o[0]  = (cg > 0) ? bf2f(p[-1]) : 0.f;
  o[17] = (cg < 7) ? bf2f(p[16]) : 0.f;
}

// ---------- K_stage: fat pipelined dispatch. roles: [pw(t-1) | dw(t-2) | cvt(t)] ----------
__global__ void __launch_bounds__(256) k_stage(
    int t, int npw, int ndw,
    const u16* __restrict__ Wb, u16* __restrict__ Bt,
    u16* __restrict__ T0, u16* __restrict__ qkvx, u16* __restrict__ qkvm,
    const float* __restrict__ x, const float* __restrict__ msg,
    const float* __restrict__ dww, float* __restrict__ ssq){
  __shared__ __align__(16) u16 smem[16384];   // 32 KB, aliased per role
  int bid = blockIdx.x;
  int tid = threadIdx.x;

  if (bid < npw){
    // ======== role PW: T[par] = Wb @ Bt[z]^T,  z = t-1 ========
    int z = t - 1, par = z & 1;
    const u16* B = Bt + (size_t)z * HW * CDIM;
    u16* As = smem;            // [2][4096] u16
    u16* Bs = smem + 8192;
    int swz = (bid & 7) * 144 + (bid >> 3);   // bijective XCD swizzle (1152 % 8 == 0)
    int bx = swz % 9, by = swz / 9;
    int m0 = bx * 128, n0 = by * 128;
    int w = tid >> 6, lane = tid & 63;
    int wy = w >> 1, wx = w & 1;
    int lm = lane & 15, q = lane >> 4;

    int srow = w * 16 + (lane >> 2);
    int scol = (lane & 3) * 8;
    const u16* ga = Wb + (size_t)(m0 + srow) * CDIM + scol;
    const u16* gb = B + (size_t)(n0 + srow) * CDIM + scol;
    u16* la = As + srow * 32 + scol;
    u16* lb = Bs + srow * 32 + scol;

    f32x4 acc[4][4];
    #pragma unroll
    for (int i = 0; i < 4; i++)
      #pragma unroll
      for (int j = 0; j < 4; j++) acc[i][j] = (f32x4){0.f,0.f,0.f,0.f};

#define PW_STAGE(buf, k0) do{ \
      gl_lds16(ga + (k0),             la + (buf) * 4096); \
      gl_lds16(ga + 64*CDIM + (k0),   la + (buf) * 4096 + 2048); \
      gl_lds16(gb + (k0),             lb + (buf) * 4096); \
      gl_lds16(gb + 64*CDIM + (k0),   lb + (buf) * 4096 + 2048); \
    }while(0)

    PW_STAGE(0, 0);
    __syncthreads();
    int cur = 0;
    for (int kt = 0; kt < 12; kt++){
      if (kt < 11) PW_STAGE(cur ^ 1, (kt + 1) * 32);
      bf16x8 af[4], bfr[4];
      #pragma unroll
      for (int i = 0; i < 4; i++)
        af[i] = *(const bf16x8*)&As[cur * 4096 + (wy * 64 + i * 16 + lm) * 32 + q * 8];
      #pragma unroll
      for (int j = 0; j < 4; j++)
        bfr[j] = *(const bf16x8*)&Bs[cur * 4096 + (wx * 64 + j * 16 + lm) * 32 + q * 8];
      #pragma unroll
      for (int i = 0; i < 4; i++)
        #pragma unroll
        for (int j = 0; j < 4; j++)
          acc[i][j] = __builtin_amdgcn_mfma_f32_16x16x32_bf16(af[i], bfr[j], acc[i][j], 0, 0, 0);
      __syncthreads();
      cur ^= 1;
    }
#undef PW_STAGE
    #pragma unroll
    for (int i = 0; i < 4; i++){
      #pragma unroll
      for (int r = 0; r < 4; r++){
        int row = m0 + wy * 64 + i * 16 + q * 4 + r;
        u16* cp = t_row(T0, qkvm, par, row) + n0 + wx * 64 + lm;
        #pragma unroll
        for (int j = 0; j < 4; j++)
          cp[j * 16] = f2bf(acc[i][j][r]);
      }
    }

  } else if (bid < npw + ndw){
    // ======== role DW: depthwise 3x3 on T[z&1], z = t-2 ========
    int ch = bid - npw;
    int z = t - 2, par = z & 1;
    const u16* src = t_row(T0, qkvm, par, ch);
    u16* dst;
    if (ch < 2 * CDIM){
      u16* qd = ((z >> 2) ? qkvm : qkvx) + (size_t)(z & 3) * QKVC * HW;
      dst = qd + (size_t)ch * HW;
    } else {
      dst = Bt + (size_t)z * HW * CDIM + (size_t)(ch - 2 * CDIM) * HW;
    }
    float w[9];
    #pragma unroll
    for (int t9 = 0; t9 < 9; t9++) w[t9] = dww[ch * 9 + t9];
    int rg = tid >> 3, cg = tid & 7;
    int r0 = rg * 4;
    float ra[18], rb[18], rc[18];
    loadrow(src, r0 - 1, cg, ra);
    loadrow(src, r0,     cg, rb);
    float ss = 0.f;
    #pragma unroll
    for (int rr = 0; rr < 4; rr++){
      int r = r0 + rr;
      loadrow(src, r + 1, cg, rc);
      u32 pk[8];
      #pragma unroll
      for (int xx = 0; xx < 16; xx++){
        float a2 = w[0] * ra[xx];
        a2 = fmaf(w[1], ra[xx + 1], a2);
        a2 = fmaf(w[2], ra[xx + 2], a2);
        a2 = fmaf(w[3], rb[xx],     a2);
        a2 = fmaf(w[4], rb[xx + 1], a2);
        a2 = fmaf(w[5], rb[xx + 2], a2);
        a2 = fmaf(w[6], rc[xx],     a2);
        a2 = fmaf(w[7], rc[xx + 1], a2);
        a2 = fmaf(w[8], rc[xx + 2], a2);
        ss = fmaf(a2, a2, ss);
        u16 hv = f2bf(a2);
        if (xx & 1) pk[xx >> 1] |= (u32)hv << 16;
        else        pk[xx >> 1]  = (u32)hv;
      }
      *(uint4*)(dst + (size_t)r * IMG + cg * 16)     = *(uint4*)&pk[0];
      *(uint4*)(dst + (size_t)r * IMG + cg * 16 + 8) = *(uint4*)&pk[4];
      #pragma unroll
      for (int ii = 0; ii < 18; ii++){ ra[ii] = rb[ii]; rb[ii] = rc[ii]; }
    }
    if (ch < 2 * CDIM){
      float* red = (float*)smem;
      red[tid] = ss;
      __syncthreads();
      for (int s = 128; s > 0; s >>= 1){
        if (tid < s) red[tid] += red[tid + s];
        __syncthreads();
      }
      if (tid == 0) ssq[(size_t)z * QKVC + ch] = red[0];
    }

  } else {
    // ======== role CVT: fp32 [c][n] -> bf16 [n][c] into Bt[z], z = t ========
    int cb = bid - npw - ndw;          // 0..767
    int z = t;
    const float* src = (z < 4 ? x : msg) + (size_t)(z & 3) * CDIM * HW;
    u16* dstz = Bt + (size_t)z * HW * CDIM;
    int n0 = (cb & 127) * 128;
    int c0 = (cb >> 7) * 64;
    u16 (*tile)[130] = (u16(*)[130])smem;   // 64 x 130 u16
    #pragma unroll
    for (int i = 0; i < 8; i++){
      int c = (tid >> 5) + i * 8;
      int nq = tid & 31;
      float4 v = *(const float4*)(src + (size_t)(c0 + c) * HW + n0 + nq * 4);
      u32 p0 = (u32)f2bf(v.x) | ((u32)f2bf(v.y) << 16);
      u32 p1 = (u32)f2bf(v.z) | ((u32)f2bf(v.w) << 16);
      *(u32*)&tile[c][nq * 4]     = p0;
      *(u32*)&tile[c][nq * 4 + 2] = p1;
    }
    __syncthreads();
    #pragma unroll
    for (int u = 0; u < 2; u++){
      int idx = tid + u * 256;            // 0..511
      int n = idx >> 2, j = idx & 3;
      u32 pk[8];
      #pragma unroll
      for (int p = 0; p < 8; p++)
        pk[p] = (u32)tile[j * 16 + 2 * p][n] | ((u32)tile[j * 16 + 2 * p + 1][n] << 16);
      u16* dp = dstz + (size_t)(n0 + n) * CDIM + c0 + j * 16;
      *(uint4*)dp       = *(uint4*)&pk[0];
      *(uint4*)(dp + 8) = *(uint4*)&pk[4];
    }
  }
}

// ---------- K_tail: fused [logits (512 blocks, 2x-unrolled loads) | v-transpose (8192 blocks)] ----------
#define LCHUNK 1024
__global__ void __launch_bounds__(256) k_tail(u16* __restrict__ qkvx,
                                              u16* __restrict__ qkvm,
                                              float* __restrict__ S,
                                              const u16* __restrict__ Bt){
  __shared__ u16 tile[48][136];
  int bid = blockIdx.x;
  int tid = threadIdx.x;

  if (bid < 512){
    // ---- logits: S += q . k over n-chunk; 2x unrolled, accumulation order preserved ----
    int nc = bid & 15;
    int bh = bid >> 4;
    int b = bh & 3, h = bh >> 2;
    int w = tid >> 6, lane = tid & 63;
    int wy = w >> 1, wx = w & 1;
    int lm = lane & 15, quad = lane >> 4;

    const u16* ap[3]; const u16* bp[3];
    #pragma unroll
    for (int i = 0; i < 3; i++){
      int g = wy * 48 + i * 16 + lm;
      int c = (g < 48) ? g : g - 48;
      ap[i] = ((g < 48) ? qkvx : qkvm) + ((size_t)b * QKVC + h * CHD + c) * HW;
      int d = wx * 48 + i * 16 + lm;
      int cc = (d < 48) ? d : d - 48;
      bp[i] = ((d < 48) ? qkvx : qkvm) + ((size_t)b * QKVC + CDIM + h * CHD + cc) * HW;
    }
    f32x4 acc[3][3];
    #pragma unroll
    for (int i = 0; i < 3; i++)
      #pragma unroll
      for (int j = 0; j < 3; j++) acc[i][j] = (f32x4){0.f,0.f,0.f,0.f};

    int nbeg = nc * LCHUNK + quad * 8;
    int nend = nc * LCHUNK + LCHUNK;
    for (int n = nbeg; n < nend; n += 64){
      bf16x8 af0[3], bf0[3], af1[3], bf1[3];
      #pragma unroll
      for (int i = 0; i < 3; i++){
        af0[i] = *(const bf16x8*)(ap[i] + n);
        af1[i] = *(const bf16x8*)(ap[i] + n + 32);
      }
      #pragma unroll
      for (int j = 0; j < 3; j++){
        bf0[j] = *(const bf16x8*)(bp[j] + n);
        bf1[j] = *(const bf16x8*)(bp[j] + n + 32);
      }
      #pragma unroll
      for (int i = 0; i < 3; i++)
        #pragma unroll
        for (int j = 0; j < 3; j++)
          acc[i][j] = __builtin_amdgcn_mfma_f32_16x16x32_bf16(af0[i], bf0[j], acc[i][j], 0, 0, 0);
      #pragma unroll
      for (int i = 0; i < 3; i++)
        #pragma unroll
        for (int j = 0; j < 3; j++)
          acc[i][j] = __builtin_amdgcn_mfma_f32_16x16x32_bf16(af1[i], bf1[j], acc[i][j], 0, 0, 0);
    }
    #pragma unroll
    for (int i = 0; i < 3; i++){
      #pragma unroll
      for (int r = 0; r < 4; r++){
        int g = wy * 48 + i * 16 + quad * 4 + r;
        int iq = (g >= 48) ? 1 : 0;
        int c = iq ? g - 48 : g;
        float* Sp = S + (((size_t)(iq * BATCH + b) * NHEADS + h) * CHD + c) * DD2;
        #pragma unroll
        for (int j = 0; j < 3; j++)
          atomicAdd(&Sp[wx * 48 + j * 16 + lm], acc[i][j][r]);
      }
    }
  } else {
    // ---- vt: v [c][n] (in Bt[z]) -> Vt[n][d] into qkvx/qkvm v-slots (low-conflict mapping) ----
    int v = bid - 512;
    int nb = v & 127;
    int h = (v >> 7) & 7;
    int z = v >> 10;
    int inp = z >> 2, b = z & 3;
    const u16* vcn = Bt + (size_t)z * HW * CDIM;
    int n0 = nb * 128;
    u16* vt = (h < 4 ? qkvx : qkvm) + ((size_t)b * QKVC + 2 * CDIM) * HW;  // [16384][384]
    int dbase = (h & 3) * 96 + inp * 48;
    #pragma unroll
    for (int j = 0; j < 3; j++){
      int i = tid + j * 256;            // uint4 index < 768
      int row = i >> 4, c8 = i & 15;
      uint4 vv = *(const uint4*)(vcn + (size_t)(h * 48 + row) * HW + n0 + c8 * 8);
      *(uint4*)&tile[row][c8 * 8] = vv;
    }
    __syncthreads();
    int n = tid >> 1, half = tid & 1;
    u16* dstp = vt + (size_t)(n0 + n) * CDIM + dbase + half * 24;
    #pragma unroll
    for (int u = 0; u < 3; u++){
      u32 pk[4];
      #pragma unroll
      for (int p = 0; p < 4; p++){
        int c = half * 24 + u * 8 + p * 2;
        pk[p] = (u32)tile[c][n] | ((u32)tile[c + 1][n] << 16);
      }
      *(uint4*)(dstp + u * 8) = *(uint4*)pk;
    }
  }
}

// ---------- K4a: scale by norms+temperature, softmax over d ----------
__global__ void __launch_bounds__(128) k_softmax(const float* __restrict__ S,
                                                 const float* __restrict__ ssq,
                                                 const float* __restrict__ temp,
                                                 float* __restrict__ attn){
  int row = blockIdx.x;
  int c = row % CHD;
  int h = (row / CHD) % NHEADS;
  int b = (row / (CHD * NHEADS)) % BATCH;
  int iq = row / (CHD * NHEADS * BATCH);
  int tid = threadIdx.x;
  __shared__ float sh[128];
  const float* Sp = S + (size_t)row * DD2;
  float ssq_q = ssq[(iq * BATCH + b) * QKVC + h * CHD + c];
  float nq = fmaxf(sqrtf(ssq_q), 1e-12f);
  float tmp = temp[h];
  float logit = -1e30f;
  int d = tid;
  if (d < DD2){
    float ssq_k = ssq[((d < CHD ? 0 : 1) * BATCH + b) * QKVC + CDIM + h * CHD + (d % CHD)];
    float nk = fmaxf(sqrtf(ssq_k), 1e-12f);
    logit = Sp[d] * tmp / (nq * nk);
  }
  sh[tid] = logit; __syncthreads();
  for (int s = 64; s > 0; s >>= 1){
    if (tid < s) sh[tid] = fmaxf(sh[tid], sh[tid + s]);
    __syncthreads();
  }
  float mx = sh[0]; __syncthreads();
  float e = (d < DD2) ? expf(logit - mx) : 0.f;
  sh[tid] = e; __syncthreads();
  for (int s = 64; s > 0; s >>= 1){
    if (tid < s) sh[tid] += sh[tid + s];
    __syncthreads();
  }
  float sum = sh[0];
  if (d < DD2) attn[(size_t)row * DD2 + d] = e / sum;
}

// ---------- K4b: AfinB (bf16) = W2-folded attention ----------
__global__ void __launch_bounds__(128) k_mmat(const float* __restrict__ attn,
                                              const float* __restrict__ W2,
                                              u16* __restrict__ AfinB){
  int oz = blockIdx.x;
  int h = blockIdx.y;
  int b = blockIdx.z;
  __shared__ float a1[CHD * DD2];
  __shared__ float a2[CHD * DD2];
  int tid = threadIdx.x;
  const float* A1 = attn + ((size_t)(0 * BATCH + b) * NHEADS + h) * CHD * DD2;
  const float* A2 = attn + ((size_t)(1 * BATCH + b) * NHEADS + h) * CHD * DD2;
  for (int i = tid; i < CHD * DD2; i += 128){ a1[i] = A1[i]; a2[i] = A2[i]; }
  __syncthreads();
  int e = tid;
  if (e < DD2){
    for (int oo = 0; oo < 8; oo++){
      int o = oz * 8 + oo;
      float acc = 0.f;
      #pragma unroll 4
      for (int cc = 0; cc < CHD; cc++){
        acc = fmaf(W2[o * KFIN + h * CHD + cc],        a1[cc * DD2 + e], acc);
        acc = fmaf(W2[o * KFIN + CDIM + h * CHD + cc], a2[cc * DD2 + e], acc);
      }
      AfinB[((size_t)b * CDIM + o) * KFIN + h * DD2 + e] = f2bf(acc);
    }
  }
}

// ---------- K_fin: out[b][384][16384] = AfinB[b] @ Vt[b]^T + b2 ----------
// Staging via running pointers: A offset is linear (32*t); B walks +32 with one base switch at t=11.
__global__ void __launch_bounds__(256) k_fin(const u16* __restrict__ AfB,
                                             const u16* __restrict__ qkvx,
                                             const u16* __restrict__ qkvm,
                                             const float* __restrict__ b2,
                                             float* __restrict__ out){
  __shared__ __align__(16) u16 As[2 * 4096];
  __shared__ __align__(16) u16 Bs[2 * 4096];
  int orig = blockIdx.x;
  int swz = (orig & 7) * 192 + (orig >> 3);   // bijective: 1536 % 8 == 0
  int m = swz % 3;
  int rest = swz / 3;
  int n0 = (rest & 127) * 128;
  int bz = rest >> 7;
  int m0 = m * 128;
  int tid = threadIdx.x;
  int w = tid >> 6, lane = tid & 63;
  int wy = w >> 1, wx = w & 1;
  int lm = lane & 15, q = lane >> 4;

  int srow = w * 16 + (lane >> 2);
  int scol = (lane & 3) * 8;
  const u16* A = AfB + (size_t)bz * CDIM * KFIN;
  const u16* ga  = A + (size_t)(m0 + srow) * KFIN + scol;
  const u16* gb0 = qkvx + ((size_t)bz * QKVC + 2 * CDIM) * HW + (size_t)(n0 + srow) * CDIM + scol;
  const u16* gb1 = qkvm + ((size_t)bz * QKVC + 2 * CDIM) * HW + (size_t)(n0 + srow) * CDIM + scol;
  u16* la = As + srow * 32 + scol;
  u16* lb = Bs + srow * 32 + scol;

  f32x4 acc[4][4];
  #pragma unroll
  for (int i = 0; i < 4; i++)
    #pragma unroll
    for (int j = 0; j < 4; j++) acc[i][j] = (f32x4){0.f,0.f,0.f,0.f};

#define FIN_ST(buf, pa_, pb_) do{ \
    gl_lds16((pa_),             la + (buf) * 4096); \
    gl_lds16((pa_) + 64*KFIN,   la + (buf) * 4096 + 2048); \
    gl_lds16((pb_),             lb + (buf) * 4096); \
    gl_lds16((pb_) + 64*CDIM,   lb + (buf) * 4096 + 2048); \
  }while(0)

  const u16* pA = ga;     // advances +32 each t: offset = 32*t == hp*CDIM + (t-12*hp)*32
  const u16* pB = gb0;    // +32 each t within half; resets to gb1 at t==11 -> t=12
  FIN_ST(0, pA, pB);
  __syncthreads();
  int cur = 0;
  for (int t = 0; t < 24; t++){
    const u16* nA = pA + 32;
    const u16* nB = (t == 11) ? gb1 : (pB + 32);
    if (t < 23) FIN_ST(cur ^ 1, nA, nB);
    bf16x8 af[4], bfr[4];
    #pragma unroll
    for (int i = 0; i < 4; i++)
      af[i] = *(const bf16x8*)&As[cur * 4096 + (wy * 64 + i * 16 + lm) * 32 + q * 8];
    #pragma unroll
    for (int j = 0; j < 4; j++)
      bfr[j] = *(const bf16x8*)&Bs[cur * 4096 + (wx * 64 + j * 16 + lm) * 32 + q * 8];
    #pragma unroll
    for (int i = 0; i < 4; i++)
      #pragma unroll
      for (int j = 0; j < 4; j++)
        acc[i][j] = __builtin_amdgcn_mfma_f32_16x16x32_bf16(af[i], bfr[j], acc[i][j], 0, 0, 0);
    __syncthreads();
    pA = nA; pB = nB;
    cur ^= 1;
  }
#undef FIN_ST
  #pragma unroll
  for (int i = 0; i < 4; i++){
    #pragma unroll
    for (int r = 0; r < 4; r++){
      int row = m0 + wy * 64 + i * 16 + q * 4 + r;
      float bv = b2[row];
      float* cp = out + (size_t)bz * CDIM * HW + (size_t)row * HW + n0 + wx * 64 + lm;
      #pragma unroll
      for (int j = 0; j < 4; j++)
        cp[j * 16] = acc[i][j][r] + bv;
    }
  }
}

extern "C" void kernel_launch(void* const* d_in, const int* in_sizes, int n_in,
                              void* d_out, int out_size, void* d_ws, size_t ws_size,
                              hipStream_t stream){
  const float* x      = (const float*)d_in[0];
  const float* msg    = (const float*)d_in[1];
  const float* temp   = (const float*)d_in[2];
  const float* qkv_w  = (const float*)d_in[3];
  const float* dw_w   = (const float*)d_in[4];
  const float* proj_w = (const float*)d_in[5];
  const float* lin_w  = (const float*)d_in[6];
  const float* lin_b  = (const float*)d_in[7];
  float* out = (float*)d_out;

  char* ws = (char*)d_ws;
  u16*   qkvx  = (u16*)(ws + OFF_QKVX);
  u16*   qkvm  = (u16*)(ws + OFF_QKVM);
  u16*   T0    = (u16*)(ws + OFF_T);
  float* ssq   = (float*)(ws + OFF_SSQ);
  float* S     = (float*)(ws + OFF_S);
  float* attn  = (float*)(ws + OFF_ATTN);
  u16*   AfinB = (u16*)(ws + OFF_AFINB);
  float* W2    = (float*)(ws + OFF_W2);
  float* b2    = (float*)(ws + OFF_B2);
  u16*   Wb    = (u16*)(ws + OFF_WB);

  // Bt scratch lives in d_out (exactly out_size). Timeline per z (pipelined across dispatches):
  //   cvt(z)@t=z writes Bt[z] -> pw(z)@t=z+1 reads it -> dw(z)@t=z+2 overwrites it with v [c][n]
  //   -> k_tail's vt reads it -> k_fin finally overwrites d_out with the real output.
  u16* Bt = (u16*)d_out;

  hipMemsetAsync(ws + OFF_S, 0, (OFF_ATTN - OFF_S), stream);

  k_w2<<<dim3((QKVC * CDIM + 255) / 256), dim3(256), 0, stream>>>(
      proj_w, lin_w, lin_b, qkv_w, W2, b2, Wb);

  // 3-deep software pipeline: dispatch t runs pw(t-1) | dw(t-2) | cvt(t) concurrently.
  for (int t = 0; t < 10; t++){
    int npw  = (t >= 1 && t <= 8) ? 1152 : 0;
    int ndw  = (t >= 2) ? 1152 : 0;
    int ncvt = (t < 8) ? 768 : 0;
    k_stage<<<dim3(npw + ndw + ncvt), dim3(256), 0, stream>>>(
        t, npw, ndw, Wb, Bt, T0, qkvx, qkvm, x, msg, dw_w, ssq);
  }

  k_tail<<<dim3(512 + 8192), dim3(256), 0, stream>>>(qkvx, qkvm, S, Bt);
  k_softmax<<<dim3(2 * BATCH * NHEADS * CHD), dim3(128), 0, stream>>>(S, ssq, temp, attn);
  k_mmat<<<dim3(CDIM / 8, NHEADS, BATCH), dim3(128), 0, stream>>>(attn, W2, AfinB);
  k_fin<<<dim3(3 * (HW / 128) * BATCH), dim3(256), 0, stream>>>(
      AfinB, qkvx, qkvm, b2, out);
}